// Round 1
// 184.710 us; speedup vs baseline: 1.1619x; 1.1619x over previous
//
#include <hip/hip_runtime.h>
#include <math.h>

// GeoAttention on gfx950: B=2, S=2048, DIM=512, H=8, HD=64.
// bf16 MFMA (16x16x32) everywhere, fp32 accumulate.
// R9: qkv_mfma + out_mfma rebuilt m97-style — 128-wide tiles, 4 waves/block,
// double-buffered LDS staged with global_load_lds width=16 (DMA, no VGPR
// round-trip), 8 ds_read_b128 + 16 MFMA per K-step, 1 barrier per K-step.
// QKV fused into one [4096x1024]@[1024x1536] GEMM over the contiguous
// wqt|wkt|wvt region; per-head softmax epilogue unchanged (wave cols = 1 head).
// V^T now stored direct-to-global (8B packed), vbuf LDS bounce deleted.

typedef __attribute__((ext_vector_type(8))) short short8;
typedef __attribute__((ext_vector_type(4))) short bf16x4;
typedef __attribute__((ext_vector_type(4))) float f32x4;

#define MFMA(a, b, c) __builtin_amdgcn_mfma_f32_16x16x32_bf16((a), (b), (c), 0, 0, 0)

static __device__ __forceinline__ short f2bf(float f) {
    unsigned u = __float_as_uint(f);
    u += 0x7fffu + ((u >> 16) & 1u);          // round-to-nearest-even
    return (short)(u >> 16);
}

// global -> LDS direct DMA, 16B per lane, wave-uniform LDS base + lane*16
static __device__ __forceinline__ void gld_lds16(const short* g, short* l) {
    __builtin_amdgcn_global_load_lds(
        (const __attribute__((address_space(1))) unsigned int*)g,
        (__attribute__((address_space(3))) unsigned int*)l, 16, 0, 0);
}

// ---------------------------------------------------------------------------
// Prep 1: xb[4096][1024] bf16 = concat(x_real, x_imag)
// ---------------------------------------------------------------------------
__global__ __launch_bounds__(256) void convert_x(
    const float* __restrict__ xr, const float* __restrict__ xi,
    short* __restrict__ xb)
{
    int idx = blockIdx.x * 256 + threadIdx.x;
    int e = idx << 2;
    int m = e >> 10, k = e & 1023;
    const float* src = (k < 512) ? xr : xi;
    float4 t = *(const float4*)(src + (size_t)m * 512 + (k & 511));
    unsigned lo = (unsigned short)f2bf(t.x) | ((unsigned)(unsigned short)f2bf(t.y) << 16);
    unsigned hi = (unsigned short)f2bf(t.z) | ((unsigned)(unsigned short)f2bf(t.w) << 16);
    uint2 o; o.x = lo; o.y = hi;
    *(uint2*)(xb + e) = o;
}

// ---------------------------------------------------------------------------
// Prep 2: transpose + convert weights to bf16, n-major [N][K].
// wqt/wkt/wvt are contiguous in the workspace => single wcat[1536][1024].
// ---------------------------------------------------------------------------
__global__ __launch_bounds__(256) void transpose_w(
    const float* __restrict__ Wq, const float* __restrict__ Wk,
    const float* __restrict__ Wv, const float* __restrict__ Wo,
    short* __restrict__ wqt, short* __restrict__ wkt,
    short* __restrict__ wvt, short* __restrict__ wot)
{
    __shared__ float t[32][33];
    const int z = blockIdx.z;
    const float* src = (z == 0) ? Wq : (z == 1) ? Wk : (z == 2) ? Wv : Wo;
    short* dst = (z == 0) ? wqt : (z == 1) ? wkt : (z == 2) ? wvt : wot;
    const int K = (z < 3) ? 1024 : 512;
    const int N = (z < 3) ? 512 : 1024;
    const int n0 = blockIdx.x << 5, k0 = blockIdx.y << 5;
    if (n0 >= N || k0 >= K) return;
    const int tx = threadIdx.x & 31, ty = threadIdx.x >> 5;
    #pragma unroll
    for (int i = 0; i < 4; ++i)
        t[ty + 8 * i][tx] = src[(size_t)(k0 + ty + 8 * i) * N + n0 + tx];
    __syncthreads();
    #pragma unroll
    for (int i = 0; i < 4; ++i)
        dst[(size_t)(n0 + ty + 8 * i) * K + k0 + tx] = f2bf(t[tx][ty + 8 * i]);
}

// ---------------------------------------------------------------------------
// Kernel 1: QKV projection, m97-style. Grid (12, 32), 256 threads = 4 waves.
// Block tile = 128 rows x 128 cols over K=1024 (BK=32, 32 steps).
// jb: 0-3 -> Q heads (2 per tile), 4-7 -> K, 8-11 -> V. Wave (2x2) owns
// 64x64 = exactly one head => fused softmax(64)+sqrt epilogue per wave.
// ---------------------------------------------------------------------------
__global__ __launch_bounds__(256, 3) void qkv_mfma(
    const short* __restrict__ xb, const short* __restrict__ wcat,
    const float* __restrict__ bq, const float* __restrict__ bk,
    const float* __restrict__ bv,
    short* __restrict__ sp, short* __restrict__ sq, short* __restrict__ vt)
{
    __shared__ short As[2][128 * 32];     // [row][k] 8KB per buffer
    __shared__ short Bs[2][128 * 32];
    const int jb = blockIdx.x;            // col tile 0..11
    const int m0 = blockIdx.y << 7;       // 128-row tile
    const int tid = threadIdx.x;
    const int w = tid >> 6, lane = tid & 63;
    const int l = lane & 15, quad = lane >> 4;

    // staging: wave w owns 1KB chunks {w, w+4} of each 8KB tile.
    // chunk c = rows [c*16, c*16+16); lane covers row c*16+(lane>>2), 16B col (lane&3)*8
    const short* gA = xb   + (size_t)(m0        + (w << 4) + (lane >> 2)) * 1024 + ((lane & 3) << 3);
    const short* gB = wcat + (size_t)((jb << 7) + (w << 4) + (lane >> 2)) * 1024 + ((lane & 3) << 3);

    // prologue: k-tile 0 -> buffer 0
    gld_lds16(gA,             &As[0][w << 9]);
    gld_lds16(gA + 64 * 1024, &As[0][(w + 4) << 9]);
    gld_lds16(gB,             &Bs[0][w << 9]);
    gld_lds16(gB + 64 * 1024, &Bs[0][(w + 4) << 9]);
    __syncthreads();

    const f32x4 z4 = {0.f, 0.f, 0.f, 0.f};
    f32x4 acc[4][4];
    #pragma unroll
    for (int i = 0; i < 4; ++i)
        #pragma unroll
        for (int j = 0; j < 4; ++j) acc[i][j] = z4;

    const int rsel = (w >> 1) << 6;   // wave row offset in tile (0/64)
    const int csel = (w & 1) << 6;    // wave col offset in tile (0/64)

    for (int kt = 0; kt < 32; ++kt) {
        const int cb = kt & 1, nb = cb ^ 1;
        if (kt < 31) {
            const int k0 = (kt + 1) << 5;
            gld_lds16(gA + k0,             &As[nb][w << 9]);
            gld_lds16(gA + k0 + 64 * 1024, &As[nb][(w + 4) << 9]);
            gld_lds16(gB + k0,             &Bs[nb][w << 9]);
            gld_lds16(gB + k0 + 64 * 1024, &Bs[nb][(w + 4) << 9]);
        }
        const short* Al = &As[cb][rsel << 5];
        const short* Bl = &Bs[cb][csel << 5];
        short8 af[4], bfr[4];
        #pragma unroll
        for (int i = 0; i < 4; ++i)
            af[i] = *(const short8*)(Al + (((i << 4) + l) << 5) + (quad << 3));
        #pragma unroll
        for (int j = 0; j < 4; ++j)
            bfr[j] = *(const short8*)(Bl + (((j << 4) + l) << 5) + (quad << 3));
        #pragma unroll
        for (int i = 0; i < 4; ++i)
            #pragma unroll
            for (int j = 0; j < 4; ++j)
                acc[i][j] = MFMA(af[i], bfr[j], acc[i][j]);
        __syncthreads();
    }

    const int op = jb >> 2;                       // 0=Q 1=K 2=V
    const int h  = ((jb & 3) << 1) | (w & 1);     // head for this wave

    if (op < 2) {
        short* dst = (op == 0) ? sp : sq;
        const float* bias = (op == 0) ? bq : bk;
        float bcol[4];
        #pragma unroll
        for (int nt = 0; nt < 4; ++nt) bcol[nt] = bias[(h << 6) + (nt << 4) + l];
        #pragma unroll
        for (int i = 0; i < 4; ++i) {
            #pragma unroll
            for (int reg = 0; reg < 4; ++reg) {
                const int r = m0 + rsel + (i << 4) + (quad << 2) + reg;
                const int b = r >> 11, s = r & 2047;
                float v[4];
                #pragma unroll
                for (int nt = 0; nt < 4; ++nt) v[nt] = acc[i][nt][reg] + bcol[nt];
                float mx = fmaxf(fmaxf(v[0], v[1]), fmaxf(v[2], v[3]));
                #pragma unroll
                for (int msk = 1; msk < 16; msk <<= 1) mx = fmaxf(mx, __shfl_xor(mx, msk));
                float e[4], ssum = 0.f;
                #pragma unroll
                for (int nt = 0; nt < 4; ++nt) { e[nt] = __expf(v[nt] - mx); ssum += e[nt]; }
                #pragma unroll
                for (int msk = 1; msk < 16; msk <<= 1) ssum += __shfl_xor(ssum, msk);
                float inv = 1.0f / ssum;
                short* o = dst + ((size_t)((b << 3) + h) * 2048 + s) * 64 + l;
                #pragma unroll
                for (int nt = 0; nt < 4; ++nt)
                    o[nt << 4] = f2bf(sqrtf(e[nt] * inv));
            }
        }
    } else {
        // V: store transposed directly, vt[b,h,d,s]; lane owns 4 consecutive s
        float bcol[4];
        #pragma unroll
        for (int nt = 0; nt < 4; ++nt) bcol[nt] = bv[(h << 6) + (nt << 4) + l];
        #pragma unroll
        for (int i = 0; i < 4; ++i) {
            const int sb = m0 + rsel + (i << 4) + (quad << 2);
            const int b = sb >> 11, s = sb & 2047;
            #pragma unroll
            for (int nt = 0; nt < 4; ++nt) {
                const int d = (nt << 4) + l;
                bf16x4 pk;
                #pragma unroll
                for (int reg = 0; reg < 4; ++reg)
                    pk[reg] = f2bf(acc[i][nt][reg] + bcol[nt]);
                *(bf16x4*)(vt + ((size_t)((b << 3) + h) * 64 + d) * 2048 + s) = pk;
            }
        }
    }
}

// ---------------------------------------------------------------------------
// Kernel 2: attention. Grid (32, 16), 256 threads = 4 waves. (unchanged R8)
// ---------------------------------------------------------------------------
__global__ __launch_bounds__(256, 4) void attn_mfma(
    const short* __restrict__ sp, const short* __restrict__ sq,
    const short* __restrict__ vt, short* __restrict__ attB)
{
    __shared__ short sqT[2][64 * 72];           // [j][d] staged sq tile
    __shared__ short vtT[2][64 * 72];           // [d][j] staged vt tile
    __shared__ short Pb[4][16 * 72];            // per-wave P [row][j]
    __shared__ float denB[4][16];
    const int bh = blockIdx.y;
    const int m0 = blockIdx.x << 6;
    const int tid = threadIdx.x;
    const int w = tid >> 6, lane = tid & 63;
    const int l = lane & 15, quad = lane >> 4;

    const short* spB = sp + (size_t)bh * 2048 * 64;
    const short* sqB = sq + (size_t)bh * 2048 * 64;
    const short* vtB = vt + (size_t)bh * 64 * 2048;

    // persistent sp frags (B-operand): lane l holds sp row (m0+w*16+l)
    const short* apr = spB + (size_t)(m0 + w * 16 + l) * 64 + quad * 8;
    short8 aq0 = *(const short8*)(apr);
    short8 aq1 = *(const short8*)(apr + 32);

    // staging assignment: thread -> tile row (tid>>2), 16-short col (tid&3)*16
    const int srow = tid >> 2;
    const int scol = (tid & 3) * 16;
    const short* sqG = sqB + (size_t)srow * 64 + scol;   // + j0*64 per jt
    const short* vtG = vtB + (size_t)srow * 2048 + scol; // + j0 per jt (cols j)
    const int ldsOff = srow * 72 + scol;

    // prologue: stage jt=0 into buffer 0
    {
        short8 a0 = *(const short8*)(sqG);
        short8 a1 = *(const short8*)(sqG + 8);
        short8 b0 = *(const short8*)(vtG);
        short8 b1 = *(const short8*)(vtG + 8);
        *(short8*)(&sqT[0][ldsOff])     = a0;
        *(short8*)(&sqT[0][ldsOff + 8]) = a1;
        *(short8*)(&vtT[0][ldsOff])     = b0;
        *(short8*)(&vtT[0][ldsOff + 8]) = b1;
    }
    __syncthreads();

    const f32x4 z4 = {0.f, 0.f, 0.f, 0.f};
    f32x4 acc[4] = {z4, z4, z4, z4};
    float den = 0.f;
    short* Pw = &Pb[w][0];

    #pragma unroll 1
    for (int jt = 0; jt < 32; ++jt) {
        const int cb = jt & 1, nb = cb ^ 1;
        const int j0n = ((jt + 1) & 31) << 6;   // wrap: harmless re-stage
        // global loads for jt+1 (latency covered by compute below)
        short8 na0 = *(const short8*)(sqG + (size_t)j0n * 64);
        short8 na1 = *(const short8*)(sqG + (size_t)j0n * 64 + 8);
        short8 nb0 = *(const short8*)(vtG + j0n);
        short8 nb1 = *(const short8*)(vtG + j0n + 8);

        // QK^T transposed: C[j][r] -> lane l = Q-row, quad*4+reg = j-local
        const short* sqL = &sqT[cb][0];
        #pragma unroll
        for (int nt = 0; nt < 4; ++nt) {
            const short* ar = sqL + (nt * 16 + l) * 72 + quad * 8;
            short8 sa0 = *(const short8*)(ar);
            short8 sa1 = *(const short8*)(ar + 32);
            f32x4 p = MFMA(sa0, aq0, z4);
            p = MFMA(sa1, aq1, p);
            float wv[4];
            #pragma unroll
            for (int reg = 0; reg < 4; ++reg) {
                // bc in [0,1]; acos(x)^2 = 2u + u^2/3 + ..., u = 1-x
                float u = fmaxf(1.0f - p[reg], 0.0f);
                float t = 0.000922f;
                t = fmaf(t, u, 0.00152228f);
                t = fmaf(t, u, 0.00384801f);
                t = fmaf(t, u, 0.01015873f);
                t = fmaf(t, u, 0.02857143f);
                t = fmaf(t, u, 0.08888889f);
                t = fmaf(t, u, 0.33333333f);
                t = fmaf(t, u, 2.0f);
                float e = __expf(-u * t);
                wv[reg] = e;
                den += e;
            }
            // pack 4 consecutive-j bf16 (trunc; bias cancels in num/den)
            uint2 pk;
            pk.x = (__float_as_uint(wv[0]) >> 16) | (__float_as_uint(wv[1]) & 0xffff0000u);
            pk.y = (__float_as_uint(wv[2]) >> 16) | (__float_as_uint(wv[3]) & 0xffff0000u);
            *(uint2*)(&Pw[l * 72 + nt * 16 + quad * 4]) = pk;
        }

        // PV: P rows as A-frags (2 reads feed 8 MFMAs), V B-frags from LDS
        const short* pr = Pw + l * 72 + quad * 8;
        short8 pa0 = *(const short8*)(pr);
        short8 pa1 = *(const short8*)(pr + 32);
        const short* vL = &vtT[cb][0];
        #pragma unroll
        for (int t4 = 0; t4 < 4; ++t4) {
            const short* vr = vL + (t4 * 16 + l) * 72 + quad * 8;
            short8 vb0 = *(const short8*)(vr);
            short8 vb1 = *(const short8*)(vr + 32);
            acc[t4] = MFMA(pa0, vb0, acc[t4]);
            acc[t4] = MFMA(pa1, vb1, acc[t4]);
        }

        // write next tiles into the other buffer, then single barrier
        *(short8*)(&sqT[nb][ldsOff])     = na0;
        *(short8*)(&sqT[nb][ldsOff + 8]) = na1;
        *(short8*)(&vtT[nb][ldsOff])     = nb0;
        *(short8*)(&vtT[nb][ldsOff + 8]) = nb1;
        __syncthreads();
    }

    // den: each quad covered different j -> sum across quads (lane row = l)
    den += __shfl_xor(den, 16);
    den += __shfl_xor(den, 32);
    if (lane < 16) denB[w][l] = den;
    // wave-synchronous LDS: compiler inserts lgkmcnt wait
    float invd[4];
    #pragma unroll
    for (int reg = 0; reg < 4; ++reg)
        invd[reg] = 1.0f / denB[w][quad * 4 + reg];

    const int b = bh >> 3, hh = bh & 7;
    #pragma unroll
    for (int t4 = 0; t4 < 4; ++t4)
        #pragma unroll
        for (int reg = 0; reg < 4; ++reg) {
            const int row = m0 + w * 16 + quad * 4 + reg;
            attB[((size_t)(b * 2048 + row)) * 512 + hh * 64 + t4 * 16 + l] =
                f2bf(acc[t4][reg] * invd[reg]);
        }
}

// ---------------------------------------------------------------------------
// Kernel 3: out = attB[4096][512](bf16) @ Wo + bo -> fp32, m97-style.
// Grid (16, 32), 256 threads = 4 waves. Tile 128 rows x 64 cols, K=512.
// ---------------------------------------------------------------------------
__global__ __launch_bounds__(256, 3) void out_mfma(
    const short* __restrict__ attB, const short* __restrict__ wot,
    const float* __restrict__ bo, float* __restrict__ out)
{
    __shared__ short As[2][128 * 32];     // 8KB per buffer
    __shared__ short Bs[2][64 * 32];      // 4KB per buffer
    const int nb0 = blockIdx.x << 6;      // 64-col tile
    const int m0 = blockIdx.y << 7;
    const int tid = threadIdx.x;
    const int w = tid >> 6, lane = tid & 63;
    const int l = lane & 15, quad = lane >> 4;

    const short* gA = attB + (size_t)(m0  + (w << 4) + (lane >> 2)) * 512 + ((lane & 3) << 3);
    const short* gB = wot  + (size_t)(nb0 + (w << 4) + (lane >> 2)) * 512 + ((lane & 3) << 3);

    // prologue: k-tile 0 -> buffer 0 (A: chunks w, w+4; B: chunk w)
    gld_lds16(gA,            &As[0][w << 9]);
    gld_lds16(gA + 64 * 512, &As[0][(w + 4) << 9]);
    gld_lds16(gB,            &Bs[0][w << 9]);
    __syncthreads();

    const f32x4 z4 = {0.f, 0.f, 0.f, 0.f};
    f32x4 acc[4][2];
    #pragma unroll
    for (int i = 0; i < 4; ++i) { acc[i][0] = z4; acc[i][1] = z4; }

    const int rsel = (w >> 1) << 6;   // wave row offset (0/64)
    const int csel = (w & 1) << 5;    // wave col offset (0/32)

    for (int kt = 0; kt < 16; ++kt) {
        const int cb = kt & 1, nbuf = cb ^ 1;
        if (kt < 15) {
            const int k0 = (kt + 1) << 5;
            gld_lds16(gA + k0,            &As[nbuf][w << 9]);
            gld_lds16(gA + k0 + 64 * 512, &As[nbuf][(w + 4) << 9]);
            gld_lds16(gB + k0,            &Bs[nbuf][w << 9]);
        }
        const short* Al = &As[cb][rsel << 5];
        const short* Bl = &Bs[cb][csel << 5];
        short8 af[4], bfr[2];
        #pragma unroll
        for (int i = 0; i < 4; ++i)
            af[i] = *(const short8*)(Al + (((i << 4) + l) << 5) + (quad << 3));
        #pragma unroll
        for (int j = 0; j < 2; ++j)
            bfr[j] = *(const short8*)(Bl + (((j << 4) + l) << 5) + (quad << 3));
        #pragma unroll
        for (int i = 0; i < 4; ++i) {
            acc[i][0] = MFMA(af[i], bfr[0], acc[i][0]);
            acc[i][1] = MFMA(af[i], bfr[1], acc[i][1]);
        }
        __syncthreads();
    }

    const int n0 = nb0 + csel;
    float bcol[2];
    bcol[0] = bo[n0 + l];
    bcol[1] = bo[n0 + 16 + l];
    #pragma unroll
    for (int i = 0; i < 4; ++i)
        #pragma unroll
        for (int reg = 0; reg < 4; ++reg) {
            const int m = m0 + rsel + (i << 4) + (quad << 2) + reg;
            float* o = out + (size_t)m * 1024 + n0 + l;
            o[0]  = acc[i][0][reg] + bcol[0];
            o[16] = acc[i][1][reg] + bcol[1];
        }
}

// ---------------------------------------------------------------------------
extern "C" void kernel_launch(void* const* d_in, const int* in_sizes, int n_in,
                              void* d_out, int out_size, void* d_ws, size_t ws_size,
                              hipStream_t stream) {
    const float* xr = (const float*)d_in[0];
    const float* xi = (const float*)d_in[1];
    const float* Wq = (const float*)d_in[2];
    const float* bq = (const float*)d_in[3];
    const float* Wk = (const float*)d_in[4];
    const float* bk = (const float*)d_in[5];
    const float* Wv = (const float*)d_in[6];
    const float* bv = (const float*)d_in[7];
    const float* Wo = (const float*)d_in[8];
    const float* bo = (const float*)d_in[9];
    float* out = (float*)d_out;

    short* base = (short*)d_ws;
    short* xb   = base;                      // 4096*1024
    short* wqt  = xb  + 4194304;             // 512*1024  } contiguous =>
    short* wkt  = wqt + 524288;              // 512*1024  } wcat[1536][1024]
    short* wvt  = wkt + 524288;              // 512*1024  }
    short* wot  = wvt + 524288;              // 1024*512
    short* spW  = wot + 524288;              // 16*2048*64
    short* sqW  = spW + 2097152;
    short* vtW  = sqW + 2097152;             // [b,h,d,s]
    short* attB = vtW + 2097152;             // 4096*512
    // total = 14,680,064 shorts = 28 MB

    hipLaunchKernelGGL(convert_x, dim3(4096), dim3(256), 0, stream, xr, xi, xb);
    hipLaunchKernelGGL(transpose_w, dim3(32, 32, 4), dim3(256), 0, stream,
                       Wq, Wk, Wv, Wo, wqt, wkt, wvt, wot);
    hipLaunchKernelGGL(qkv_mfma, dim3(12, 32), dim3(256), 0, stream,
                       xb, wqt, bq, bk, bv, spW, sqW, vtW);
    hipLaunchKernelGGL(attn_mfma, dim3(32, 16), dim3(256), 0, stream,
                       spW, sqW, vtW, attB);
    hipLaunchKernelGGL(out_mfma, dim3(16, 32), dim3(256), 0, stream,
                       attB, wot, bo, out);
}